// Round 1
// baseline (358.133 us; speedup 1.0000x reference)
//
#include <hip/hip_runtime.h>

#define D 64

typedef __attribute__((ext_vector_type(8))) short short8;   // 8 bf16 = 4 VGPRs
typedef __attribute__((ext_vector_type(4))) float floatx4;  // MFMA C/D

__device__ __forceinline__ ushort f2bf(float f) {     // fp32 -> bf16, RNE
    unsigned u = __float_as_uint(f);
    u += 0x7fffu + ((u >> 16) & 1u);
    return (ushort)(u >> 16);
}
__device__ __forceinline__ float bf2f(ushort h) {
    return __int_as_float(((unsigned)h) << 16);
}

// ---------------- cast x to bf16 rows + zero cnt/cur + init hist/bincur0/total ----
__global__ void cast_kernel(const float* __restrict__ x, ushort* __restrict__ xh,
                            int* __restrict__ cnt, int* __restrict__ cur,
                            int* __restrict__ hist, int* __restrict__ bincur0,
                            int* __restrict__ total, int n4, int N) {
    int i = blockIdx.x * blockDim.x + threadIdx.x;
    if (i < N) { cnt[i] = 0; cur[i] = 0; }
    if (i < 64) { hist[i] = 0; bincur0[i] = 0; }
    if (i == 0) *total = 0;
    if (i >= n4) return;
    float4 v = ((const float4*)x)[i];
    ushort4 r;
    r.x = f2bf(v.x); r.y = f2bf(v.y); r.z = f2bf(v.z); r.w = f2bf(v.w);
    ((ushort4*)xh)[i] = r;
}

// ---------------- degree count: edge-parallel, L2-resident atomics --------------
__global__ void deg_kernel(const int* __restrict__ ei, int* __restrict__ cnt, int E) {
    int e = blockIdx.x * blockDim.x + threadIdx.x;
    if (e < E) atomicAdd(&cnt[ei[E + e]], 1);
}

// ---------------- alloc: wave-scan of degrees -> beg, plus degree histogram -----
__global__ void alloc_kernel(const int* __restrict__ cnt, int* __restrict__ beg,
                             int* __restrict__ total, int* __restrict__ hist, int N) {
    __shared__ int lh[64];
    int tid = threadIdx.x;
    if (tid < 64) lh[tid] = 0;
    __syncthreads();
    int i = blockIdx.x * blockDim.x + tid;
    int lane = tid & 63;
    int c = (i < N) ? cnt[i] : 0;
    if (i < N) atomicAdd(&lh[c < 63 ? c : 63], 1);
    int p = c;
#pragma unroll
    for (int o = 1; o < 64; o <<= 1) {
        int u = __shfl_up(p, o, 64);
        if (lane >= o) p += u;
    }
    int wavetot = __shfl(p, 63, 64);
    int base = 0;
    if (lane == 63) base = atomicAdd(total, wavetot);
    base = __shfl(base, 63, 64);
    if (i < N) beg[i] = base + p - c;
    __syncthreads();
    if (tid < 64 && lh[tid] > 0) atomicAdd(&hist[tid], lh[tid]);
}

// ---------------- fused: scatter nodes into DESCENDING-degree perm + CSR fill ---
// Blocks whose node range < N do the perm scatter; all blocks do the edge fill.
__global__ void scatter_fill_kernel(const int* __restrict__ ei,
                                    const int* __restrict__ cnt, const int* __restrict__ hist,
                                    int* __restrict__ bincur0, int* __restrict__ perm,
                                    const int* __restrict__ beg, int* __restrict__ cur,
                                    int* __restrict__ srclist, int N, int E) {
    __shared__ int lh[64];
    __shared__ int lbase[64];
    __shared__ int sbase[64];
    int tid = threadIdx.x;
    int gbase = blockIdx.x * blockDim.x;
    if (gbase < N) {                       // ---- scatter role (blocks covering nodes)
        if (tid < 64) {
            lh[tid] = 0;
            int c = hist[tid];
            int p = c;
#pragma unroll
            for (int o = 1; o < 64; o <<= 1) {
                int u = __shfl_up(p, o, 64);
                if (tid >= o) p += u;
            }
            sbase[tid] = N - p;            // suffix sum: high-degree bins first
        }
        __syncthreads();
        int i = gbase + tid;
        int bin = 0, slot = 0;
        if (i < N) {
            int c = cnt[i];
            bin = c < 63 ? c : 63;
            slot = atomicAdd(&lh[bin], 1);
        }
        __syncthreads();
        if (tid < 64 && lh[tid] > 0) lbase[tid] = sbase[tid] + atomicAdd(&bincur0[tid], lh[tid]);
        __syncthreads();
        if (i < N) perm[lbase[bin] + slot] = i;
    }
    // ---- fill role (all blocks): srclist[beg[dst] + cursor++] = src
    int e = gbase + tid;
    if (e < E) {
        int src = ei[e];
        int dst = ei[E + e];
        int pos = beg[dst] + atomicAdd(&cur[dst], 1);
        srclist[pos] = src;
    }
}

// ---------------- fused SAGE layer: bf16 gather + MFMA combine ----------------
// 16 nodes per wave via degree-sorted perm (uniform degree -> md ~= deg).
// Lane L = (q=L>>4, m=L&15): gather accumulates the lane's MFMA A-frag features
// of node perm[base+m]; combine = 16 mfma_f32_16x16x32_bf16 with LDS B-frags.
// launch_bounds(256,8): 64 VGPR cap (already met), 8 blocks/CU -> whole grid
// (1563 blocks) co-resident in one batch.

__global__ void __launch_bounds__(256, 8) sage_kernel(
    const ushort* __restrict__ inh,      // bf16 rows [N][64]
    const int* __restrict__ perm,
    const int* __restrict__ beg_, const int* __restrict__ cnt_,
    const int* __restrict__ srclist,
    const float* __restrict__ Wl, const float* __restrict__ bl,
    const float* __restrict__ Wr,
    float* __restrict__ out_f32,         // fp32 out (layer 2) or null
    ushort* __restrict__ out_bf,         // bf16 out (layer 1) or null
    int N, int relu) {
    __shared__ short8 fL[8][64];   // [c*2+s][lane]: B-frag of Wl^T, col-tile c, k-step s
    __shared__ short8 fR[8][64];
    int tid = threadIdx.x;
    int lane = tid & 63;
    {
        int c = tid >> 6;
        int n = lane & 15;
        int q = lane >> 4;
#pragma unroll
        for (int s = 0; s < 2; ++s) {
            const float* pl = Wl + (c * 16 + n) * D + s * 32 + q * 8;
            const float* pr = Wr + (c * 16 + n) * D + s * 32 + q * 8;
            short8 vl, vr;
#pragma unroll
            for (int j = 0; j < 8; ++j) {
                vl[j] = (short)f2bf(pl[j]);
                vr[j] = (short)f2bf(pr[j]);
            }
            fL[c * 2 + s][lane] = vl;
            fR[c * 2 + s][lane] = vr;
        }
    }
    __syncthreads();

    int m = lane & 15;
    int q = lane >> 4;
    float b0 = bl[m], b1 = bl[16 + m], b2 = bl[32 + m], b3 = bl[48 + m];
    int gwave   = blockIdx.x * 4 + (tid >> 6);
    int nwaves  = gridDim.x * 4;
    int ngroups = (N + 15) >> 4;

    for (int g = gwave; g < ngroups; g += nwaves) {
        int base = g * 16;
        bool nv = (base + m) < N;
        int node = nv ? perm[base + m] : 0;
        int beg = nv ? beg_[node] : 0;   // 4 lanes per node share the address
        int deg = nv ? cnt_[node] : 0;

        // wave-max degree (uniform after sorting except at bin boundaries)
        int md = deg;
        md = max(md, __shfl_xor(md, 1, 64));
        md = max(md, __shfl_xor(md, 2, 64));
        md = max(md, __shfl_xor(md, 4, 64));
        md = max(md, __shfl_xor(md, 8, 64));

        float f0[8], f1[8];
#pragma unroll
        for (int u = 0; u < 8; ++u) { f0[u] = 0.f; f1[u] = 0.f; }

#pragma unroll 8
        for (int j = 0; j < md; ++j) {
            int idx = beg + ((j < deg) ? j : 0);
            int si = srclist[idx];
            const ushort* rp = inh + (size_t)si * D;
            short8 lo = *(const short8*)(rp + q * 8);        // features q*8..+7
            short8 hi = *(const short8*)(rp + 32 + q * 8);   // features 32+q*8..+7
            float msk = (j < deg) ? 1.f : 0.f;
#pragma unroll
            for (int u = 0; u < 8; ++u) {
                f0[u] = fmaf(msk, bf2f((ushort)lo[u]), f0[u]);
                f1[u] = fmaf(msk, bf2f((ushort)hi[u]), f1[u]);
            }
        }

        float scale = (deg > 0) ? 1.0f / (float)deg : 0.0f;
        short8 a0, a1;
#pragma unroll
        for (int u = 0; u < 8; ++u) {
            a0[u] = (short)f2bf(f0[u] * scale);
            a1[u] = (short)f2bf(f1[u] * scale);
        }

        // root rows load directly as A-fragments
        const ushort* rr = inh + (size_t)node * D;
        short8 r0 = *(const short8*)(rr + q * 8);
        short8 r1 = *(const short8*)(rr + 32 + q * 8);

#pragma unroll
        for (int c = 0; c < 4; ++c) {
            float bc = (c == 0) ? b0 : (c == 1) ? b1 : (c == 2) ? b2 : b3;
            floatx4 acc = {bc, bc, bc, bc};
            acc = __builtin_amdgcn_mfma_f32_16x16x32_bf16(a0, fL[c * 2 + 0][lane], acc, 0, 0, 0);
            acc = __builtin_amdgcn_mfma_f32_16x16x32_bf16(a1, fL[c * 2 + 1][lane], acc, 0, 0, 0);
            acc = __builtin_amdgcn_mfma_f32_16x16x32_bf16(r0, fR[c * 2 + 0][lane], acc, 0, 0, 0);
            acc = __builtin_amdgcn_mfma_f32_16x16x32_bf16(r1, fR[c * 2 + 1][lane], acc, 0, 0, 0);
#pragma unroll
            for (int r = 0; r < 4; ++r) {
                float v = acc[r];
                if (relu) v = fmaxf(v, 0.f);
                if (base + q * 4 + r < N) {
                    int onode = __shfl(node, q * 4 + r, 64);   // D row = q*4 + reg
                    size_t off = (size_t)onode * D + c * 16 + m;   // D col = lane&15
                    if (out_bf) out_bf[off] = f2bf(v);
                    else        out_f32[off] = v;
                }
            }
        }
    }
}

extern "C" void kernel_launch(void* const* d_in, const int* in_sizes, int n_in,
                              void* d_out, int out_size, void* d_ws, size_t ws_size,
                              hipStream_t stream) {
    const float* x   = (const float*)d_in[0];
    const int*   ei  = (const int*)d_in[1];
    const float* W1l = (const float*)d_in[2];
    const float* b1l = (const float*)d_in[3];
    const float* W1r = (const float*)d_in[4];
    const float* W2l = (const float*)d_in[5];
    const float* b2l = (const float*)d_in[6];
    const float* W2r = (const float*)d_in[7];
    float* out = (float*)d_out;

    int N = in_sizes[0] / D;   // 100000
    int E = in_sizes[1] / 2;   // 1000000

    char* ws = (char*)d_ws;
    // Layout (bytes):
    //   [0, N*D*2)         xh : bf16 x rows
    //   [N*D*2, 2*N*D*2)   hh : bf16 h rows; fill-phase `cur` cursor aliases here
    //                          (N ints = 400KB < 12.8MB; dead before sage1 writes hh)
    //   then srclist (+slack), beg, cnt, perm, total, hist, bincur0
    ushort* xh = (ushort*)ws;
    ushort* hh = xh + (size_t)N * D;
    int*   cur     = (int*)hh;                            // N ints (alias hh)
    int*   srclist = (int*)(ws + (size_t)2 * N * D * 2);  // E ints + 64 slack
    int*   beg     = srclist + E + 64;                    // N ints
    int*   cnt     = beg + N;                             // N ints
    int*   perm    = cnt + N;                             // N ints
    int*   total   = perm + N;                            // 1 int
    int*   hist    = total + 1;                           // 64 ints
    int*   bincur0 = hist + 64;                           // 64 ints

    int n4 = N * D / 4;
    cast_kernel<<<(n4 + 255) / 256, 256, 0, stream>>>(x, xh, cnt, cur, hist,
                                                      bincur0, total, n4, N);

    int eblocks = (E + 255) / 256;
    int nblocks = (N + 255) / 256;
    deg_kernel<<<eblocks, 256, 0, stream>>>(ei, cnt, E);
    alloc_kernel<<<nblocks, 256, 0, stream>>>(cnt, beg, total, hist, N);
    scatter_fill_kernel<<<eblocks, 256, 0, stream>>>(ei, cnt, hist, bincur0, perm,
                                                     beg, cur, srclist, N, E);

    int ngroups = (N + 15) / 16;              // 6250
    int sblocks = (ngroups + 3) / 4;          // 1 group per wave
    // layer 1: hh(bf16) = relu(mean_agg(xh)@W1l^T + b1l + xh@W1r^T)
    sage_kernel<<<sblocks, 256, 0, stream>>>(xh, perm, beg, cnt, srclist,
                                             W1l, b1l, W1r, nullptr, hh, N, 1);
    // layer 2: out(fp32) = mean_agg(hh)@W2l^T + b2l + hh@W2r^T
    sage_kernel<<<sblocks, 256, 0, stream>>>(hh, perm, beg, cnt, srclist,
                                             W2l, b2l, W2r, out, nullptr, N, 0);
}

// Round 2
// 288.827 us; speedup vs baseline: 1.2400x; 1.2400x over previous
//
#include <hip/hip_runtime.h>

#define D 64

typedef __attribute__((ext_vector_type(8))) short short8;   // 8 bf16 = 4 VGPRs
typedef __attribute__((ext_vector_type(4))) float floatx4;  // MFMA C/D

__device__ __forceinline__ ushort f2bf(float f) {     // fp32 -> bf16, RNE
    unsigned u = __float_as_uint(f);
    u += 0x7fffu + ((u >> 16) & 1u);
    return (ushort)(u >> 16);
}
__device__ __forceinline__ float bf2f(ushort h) {
    return __int_as_float(((unsigned)h) << 16);
}

// ---------------- cast x to bf16 rows + zero cnt/cur + init hist/bincur0/total ----
__global__ void cast_kernel(const float* __restrict__ x, ushort* __restrict__ xh,
                            int* __restrict__ cnt, int* __restrict__ cur,
                            int* __restrict__ hist, int* __restrict__ bincur0,
                            int* __restrict__ total, int n4, int N) {
    int i = blockIdx.x * blockDim.x + threadIdx.x;
    if (i < N) { cnt[i] = 0; cur[i] = 0; }
    if (i < 64) { hist[i] = 0; bincur0[i] = 0; }
    if (i == 0) *total = 0;
    if (i >= n4) return;
    float4 v = ((const float4*)x)[i];
    ushort4 r;
    r.x = f2bf(v.x); r.y = f2bf(v.y); r.z = f2bf(v.z); r.w = f2bf(v.w);
    ((ushort4*)xh)[i] = r;
}

// ---------------- degree count: XCD-partitioned atomics --------------------------
// part p = bid & 7 (default bid->XCD round-robin); each part owns dst range
// [N*p/8, N*(p+1)/8): cnt lines are only touched by one XCD's L2.
__global__ void deg_kernel(const int* __restrict__ ei, int* __restrict__ cnt,
                           int N, int E) {
    int p = blockIdx.x & 7;
    int slice = blockIdx.x >> 3;
    int lo = (int)(((long long)N * p) >> 3);
    int hi = (int)(((long long)N * (p + 1)) >> 3);
    int e0 = slice * 8192;
#pragma unroll 4
    for (int it = 0; it < 32; ++it) {
        int e = e0 + it * 256 + threadIdx.x;
        if (e < E) {
            int dst = ei[E + e];
            if (dst >= lo && dst < hi) atomicAdd(&cnt[dst], 1);
        }
    }
}

// ---------------- alloc: wave-scan of degrees -> beg, plus degree histogram -----
__global__ void alloc_kernel(const int* __restrict__ cnt, int* __restrict__ beg,
                             int* __restrict__ total, int* __restrict__ hist, int N) {
    __shared__ int lh[64];
    int tid = threadIdx.x;
    if (tid < 64) lh[tid] = 0;
    __syncthreads();
    int i = blockIdx.x * blockDim.x + tid;
    int lane = tid & 63;
    int c = (i < N) ? cnt[i] : 0;
    if (i < N) atomicAdd(&lh[c < 63 ? c : 63], 1);
    int p = c;
#pragma unroll
    for (int o = 1; o < 64; o <<= 1) {
        int u = __shfl_up(p, o, 64);
        if (lane >= o) p += u;
    }
    int wavetot = __shfl(p, 63, 64);
    int base = 0;
    if (lane == 63) base = atomicAdd(total, wavetot);
    base = __shfl(base, 63, 64);
    if (i < N) beg[i] = base + p - c;
    __syncthreads();
    if (tid < 64 && lh[tid] > 0) atomicAdd(&hist[tid], lh[tid]);
}

// ---------------- CSR fill: XCD-partitioned scatter ------------------------------
// srclist ranges of part-p nodes are written only by part-p blocks (one XCD):
// dirty lines stay L2-local, evicted once -> no cross-XCD write thrash.
__global__ void fill_kernel(const int* __restrict__ ei, const int* __restrict__ beg,
                            int* __restrict__ cur, int* __restrict__ srclist,
                            int N, int E) {
    int p = blockIdx.x & 7;
    int slice = blockIdx.x >> 3;
    int lo = (int)(((long long)N * p) >> 3);
    int hi = (int)(((long long)N * (p + 1)) >> 3);
    int e0 = slice * 8192;
#pragma unroll 4
    for (int it = 0; it < 32; ++it) {
        int e = e0 + it * 256 + threadIdx.x;
        if (e < E) {
            int dst = ei[E + e];
            if (dst >= lo && dst < hi) {
                int pos = beg[dst] + atomicAdd(&cur[dst], 1);
                srclist[pos] = ei[e];
            }
        }
    }
}

// ---------------- scatter nodes into DESCENDING-degree perm ----------------------
__global__ void scatter_kernel(const int* __restrict__ cnt, const int* __restrict__ hist,
                               int* __restrict__ bincur0, int* __restrict__ perm, int N) {
    __shared__ int lh[64];
    __shared__ int lbase[64];
    __shared__ int sbase[64];
    int tid = threadIdx.x;
    if (tid < 64) {
        lh[tid] = 0;
        int c = hist[tid];
        int p = c;
#pragma unroll
        for (int o = 1; o < 64; o <<= 1) {
            int u = __shfl_up(p, o, 64);
            if (tid >= o) p += u;
        }
        sbase[tid] = N - p;            // suffix base: high-degree bins first
    }
    __syncthreads();
    int i = blockIdx.x * blockDim.x + tid;
    int bin = 0, slot = 0;
    if (i < N) {
        int c = cnt[i];
        bin = c < 63 ? c : 63;
        slot = atomicAdd(&lh[bin], 1);
    }
    __syncthreads();
    if (tid < 64 && lh[tid] > 0) lbase[tid] = sbase[tid] + atomicAdd(&bincur0[tid], lh[tid]);
    __syncthreads();
    if (i < N) perm[lbase[bin] + slot] = i;
}

// ---------------- fused SAGE layer: bf16 gather + MFMA combine ----------------
// 16 nodes per wave via degree-sorted perm (uniform degree -> md ~= deg).
// Epilogue stages the 16x64 tile in per-wave LDS, then writes FULL rows
// (128B bf16 / 256B fp32) -> no partial-line RMW at HBM/L2.
// launch_bounds(256,4): VGPR cap 128, compiler lands ~64, NO spill (the (256,8)
// cap of 64 forced scratch spills: +150MB traffic, do not repeat).

__global__ void __launch_bounds__(256, 4) sage_kernel(
    const ushort* __restrict__ inh,      // bf16 rows [N][64]
    const int* __restrict__ perm,
    const int* __restrict__ beg_, const int* __restrict__ cnt_,
    const int* __restrict__ srclist,
    const float* __restrict__ Wl, const float* __restrict__ bl,
    const float* __restrict__ Wr,
    float* __restrict__ out_f32,         // fp32 out (layer 2) or null
    ushort* __restrict__ out_bf,         // bf16 out (layer 1) or null
    int N, int relu) {
    __shared__ short8 fL[8][64];   // [c*2+s][lane]: B-frag of Wl^T, col-tile c, k-step s
    __shared__ short8 fR[8][64];
    __shared__ float ot[4][16 * 68];     // per-wave out tile, stride 68 (pad: bank spread)
    int tid = threadIdx.x;
    int lane = tid & 63;
    {
        int c = tid >> 6;
        int n = lane & 15;
        int q = lane >> 4;
#pragma unroll
        for (int s = 0; s < 2; ++s) {
            const float* pl = Wl + (c * 16 + n) * D + s * 32 + q * 8;
            const float* pr = Wr + (c * 16 + n) * D + s * 32 + q * 8;
            short8 vl, vr;
#pragma unroll
            for (int j = 0; j < 8; ++j) {
                vl[j] = (short)f2bf(pl[j]);
                vr[j] = (short)f2bf(pr[j]);
            }
            fL[c * 2 + s][lane] = vl;
            fR[c * 2 + s][lane] = vr;
        }
    }
    __syncthreads();

    int m = lane & 15;
    int q = lane >> 4;
    float* otw = &ot[tid >> 6][0];
    float b0 = bl[m], b1 = bl[16 + m], b2 = bl[32 + m], b3 = bl[48 + m];
    int gwave   = blockIdx.x * 4 + (tid >> 6);
    int nwaves  = gridDim.x * 4;
    int ngroups = (N + 15) >> 4;

    for (int g = gwave; g < ngroups; g += nwaves) {
        int base = g * 16;
        bool nv = (base + m) < N;
        int node = nv ? perm[base + m] : 0;
        int beg = nv ? beg_[node] : 0;   // 4 lanes per node share the address
        int deg = nv ? cnt_[node] : 0;

        // wave-max degree (uniform after descending sort except at bin boundaries)
        int md = deg;
        md = max(md, __shfl_xor(md, 1, 64));
        md = max(md, __shfl_xor(md, 2, 64));
        md = max(md, __shfl_xor(md, 4, 64));
        md = max(md, __shfl_xor(md, 8, 64));

        float f0[8], f1[8];
#pragma unroll
        for (int u = 0; u < 8; ++u) { f0[u] = 0.f; f1[u] = 0.f; }

#pragma unroll 8
        for (int j = 0; j < md; ++j) {
            int idx = beg + ((j < deg) ? j : 0);
            int si = srclist[idx];
            const ushort* rp = inh + (size_t)si * D;
            short8 lo = *(const short8*)(rp + q * 8);        // features q*8..+7
            short8 hi = *(const short8*)(rp + 32 + q * 8);   // features 32+q*8..+7
            float msk = (j < deg) ? 1.f : 0.f;
#pragma unroll
            for (int u = 0; u < 8; ++u) {
                f0[u] = fmaf(msk, bf2f((ushort)lo[u]), f0[u]);
                f1[u] = fmaf(msk, bf2f((ushort)hi[u]), f1[u]);
            }
        }

        float scale = (deg > 0) ? 1.0f / (float)deg : 0.0f;
        short8 a0, a1;
#pragma unroll
        for (int u = 0; u < 8; ++u) {
            a0[u] = (short)f2bf(f0[u] * scale);
            a1[u] = (short)f2bf(f1[u] * scale);
        }

        // root rows load directly as A-fragments
        const ushort* rr = inh + (size_t)node * D;
        short8 r0 = *(const short8*)(rr + q * 8);
        short8 r1 = *(const short8*)(rr + 32 + q * 8);

#pragma unroll
        for (int c = 0; c < 4; ++c) {
            float bc = (c == 0) ? b0 : (c == 1) ? b1 : (c == 2) ? b2 : b3;
            floatx4 acc = {bc, bc, bc, bc};
            acc = __builtin_amdgcn_mfma_f32_16x16x32_bf16(a0, fL[c * 2 + 0][lane], acc, 0, 0, 0);
            acc = __builtin_amdgcn_mfma_f32_16x16x32_bf16(a1, fL[c * 2 + 1][lane], acc, 0, 0, 0);
            acc = __builtin_amdgcn_mfma_f32_16x16x32_bf16(r0, fR[c * 2 + 0][lane], acc, 0, 0, 0);
            acc = __builtin_amdgcn_mfma_f32_16x16x32_bf16(r1, fR[c * 2 + 1][lane], acc, 0, 0, 0);
#pragma unroll
            for (int r = 0; r < 4; ++r) {
                float v = acc[r];
                if (relu) v = fmaxf(v, 0.f);
                otw[(q * 4 + r) * 68 + c * 16 + m] = v;   // stage in LDS (wave-private)
            }
        }

        // full-row writeout: 4 lanes per node row, line-complete stores
        int rho = lane >> 2;                 // node slot 0..15
        int q4  = lane & 3;                  // quarter of the row
        int onode = __shfl(node, rho, 64);
        const float* sp = &otw[rho * 68 + q4 * 16];
        if (base + rho < N) {
            if (out_bf) {
                uint u[8];
#pragma unroll
                for (int j = 0; j < 8; ++j)
                    u[j] = (uint)f2bf(sp[2 * j]) | ((uint)f2bf(sp[2 * j + 1]) << 16);
                uint4* dp = (uint4*)(out_bf + (size_t)onode * D + q4 * 16);
                uint4 w0 = {u[0], u[1], u[2], u[3]};
                uint4 w1 = {u[4], u[5], u[6], u[7]};
                dp[0] = w0; dp[1] = w1;      // 32B/lane, 128B/row contiguous
            } else {
                float4* dp = (float4*)(out_f32 + (size_t)onode * D + q4 * 16);
                const float4* s4 = (const float4*)sp;
                dp[0] = s4[0]; dp[1] = s4[1]; dp[2] = s4[2]; dp[3] = s4[3];  // 64B/lane
            }
        }
    }
}

extern "C" void kernel_launch(void* const* d_in, const int* in_sizes, int n_in,
                              void* d_out, int out_size, void* d_ws, size_t ws_size,
                              hipStream_t stream) {
    const float* x   = (const float*)d_in[0];
    const int*   ei  = (const int*)d_in[1];
    const float* W1l = (const float*)d_in[2];
    const float* b1l = (const float*)d_in[3];
    const float* W1r = (const float*)d_in[4];
    const float* W2l = (const float*)d_in[5];
    const float* b2l = (const float*)d_in[6];
    const float* W2r = (const float*)d_in[7];
    float* out = (float*)d_out;

    int N = in_sizes[0] / D;   // 100000
    int E = in_sizes[1] / 2;   // 1000000

    char* ws = (char*)d_ws;
    // Layout (bytes):
    //   [0, N*D*2)         xh : bf16 x rows
    //   [N*D*2, 2*N*D*2)   hh : bf16 h rows; fill-phase `cur` cursor aliases here
    //                          (N ints = 400KB < 12.8MB; dead before sage1 writes hh)
    //   then srclist (+slack), beg, cnt, perm, total, hist, bincur0
    ushort* xh = (ushort*)ws;
    ushort* hh = xh + (size_t)N * D;
    int*   cur     = (int*)hh;                            // N ints (alias hh)
    int*   srclist = (int*)(ws + (size_t)2 * N * D * 2);  // E ints + 64 slack
    int*   beg     = srclist + E + 64;                    // N ints
    int*   cnt     = beg + N;                             // N ints
    int*   perm    = cnt + N;                             // N ints
    int*   total   = perm + N;                            // 1 int
    int*   hist    = total + 1;                           // 64 ints
    int*   bincur0 = hist + 64;                           // 64 ints

    int n4 = N * D / 4;
    cast_kernel<<<(n4 + 255) / 256, 256, 0, stream>>>(x, xh, cnt, cur, hist,
                                                      bincur0, total, n4, N);

    int nblocks = (N + 255) / 256;
    int nslices = (E + 8191) / 8192;
    deg_kernel<<<nslices * 8, 256, 0, stream>>>(ei, cnt, N, E);
    alloc_kernel<<<nblocks, 256, 0, stream>>>(cnt, beg, total, hist, N);
    fill_kernel<<<nslices * 8, 256, 0, stream>>>(ei, beg, cur, srclist, N, E);
    scatter_kernel<<<nblocks, 256, 0, stream>>>(cnt, hist, bincur0, perm, N);

    int ngroups = (N + 15) / 16;              // 6250
    int sblocks = (ngroups + 3) / 4;          // 1 group per wave
    // layer 1: hh(bf16) = relu(mean_agg(xh)@W1l^T + b1l + xh@W1r^T)
    sage_kernel<<<sblocks, 256, 0, stream>>>(xh, perm, beg, cnt, srclist,
                                             W1l, b1l, W1r, nullptr, hh, N, 1);
    // layer 2: out(fp32) = mean_agg(hh)@W2l^T + b2l + hh@W2r^T
    sage_kernel<<<sblocks, 256, 0, stream>>>(hh, perm, beg, cnt, srclist,
                                             W2l, b2l, W2r, out, nullptr, N, 0);
}